// Round 27
// baseline (338.459 us; speedup 1.0000x reference)
//
#include <hip/hip_runtime.h>
#include <hip/hip_bf16.h>
#include <math.h>

#define DI __device__ __forceinline__

constexpr int B = 8, C = 64, H = 128, W = 128, N = H * W;   // N = 16384
constexpr int HID = 170;
constexpr int QKVC = 3 * C;                                 // 192

typedef _Float16 half8 __attribute__((ext_vector_type(8)));
typedef _Float16 half4v __attribute__((ext_vector_type(4)));
typedef float f32x4 __attribute__((ext_vector_type(4)));

extern "C" __device__ _Float16 __ocml_exp_f16(_Float16);

// gelu exact ~= v * sigmoid(1.5957691*(v + 0.044715 v^3)); fp16 packed path.
DI half8 gelu_gate_h8(half8 a, half8 g) {
    const _Float16 k = (_Float16)0.044715f;
    const _Float16 c = (_Float16)1.5957691f;
    half8 a2 = a * a;
    half8 t = a * ((_Float16)1.f + k * a2);   // packed v_pk ops
    half8 o;
#pragma unroll
    for (int i = 0; i < 8; ++i) {
        _Float16 e = __ocml_exp_f16((_Float16)(-c * t[i]));
        o[i] = (_Float16)(a[i] / ((_Float16)1.f + e) * g[i]);
    }
    return o;
}

// shift-window helper: given aligned row ptr, produce left/center/right windows
DI void row_win(const _Float16* __restrict__ rp, int x0, half8& sL, half8& m, half8& sR) {
    m = *(const half8*)rp;
    half8 pv = {0, 0, 0, 0, 0, 0, 0, 0};
    half8 nv = {0, 0, 0, 0, 0, 0, 0, 0};
    pv[7] = (x0 > 0) ? rp[-1] : (_Float16)0.f;
    nv[0] = (x0 < 120) ? rp[8] : (_Float16)0.f;
    sL = __builtin_shufflevector(pv, m, 7, 8, 9, 10, 11, 12, 13, 14);
    sR = __builtin_shufflevector(m, nv, 1, 2, 3, 4, 5, 6, 7, 8);
}

// ---- device-side weight pack into MFMA A-fragment order (fp32 -> fp16) ----
DI void wpack_dev(const float* __restrict__ Wm, const float* __restrict__ lnsc,
                  int OREAL, int KREAL, int KT, _Float16* __restrict__ out,
                  int f, int l)
{
    int mt = f / KT, kt = f % KT;
    int row = mt * 16 + (l & 15);
    int col0 = kt * 32 + (l >> 4) * 8;
    half8 v;
#pragma unroll
    for (int i = 0; i < 8; ++i) {
        int col = col0 + i;
        float w = (row < OREAL && col < KREAL) ? Wm[row * KREAL + col] : 0.f;
        if (lnsc && col < KREAL) w *= lnsc[col];
        v[i] = (_Float16)w;
    }
    *(half8*)(out + (size_t)f * 512 + l * 8) = v;
}

// ---- device-side bias fold: biasv[o] = sum_c W[o,c]*lnb[c]; zero-pad to OPAD ----
DI void wbias_dev(const float* __restrict__ Wm, const float* __restrict__ lnb,
                  int OREAL, int OPAD, float* __restrict__ biasv, int blk, int l)
{
    int o = blk * 64 + l;
    if (o >= OPAD) return;
    float s = 0.f;
    if (o < OREAL) {
#pragma unroll
        for (int c = 0; c < 64; ++c) s += Wm[o * 64 + c] * lnb[c];
    }
    biasv[o] = s;
}

// =========== single prep kernel: all weight packs + LN-fold biases ===========
__global__ __launch_bounds__(64) void prep_kernel(
    const float* rsa_qkv_w, const float* ln_s0_w, const float* ln_s0_b,
    const float* gsa_qkv_w, const float* ln_c0_w, const float* ln_c0_b,
    const float* ffs_in_w,  const float* ln_s2_w, const float* ln_s2_b,
    const float* ffc_in_w,  const float* ln_c2_w, const float* ln_c2_b,
    const float* ffs_out_w, const float* ffc_out_w, const float* rsa_proj_w,
    _Float16* wp_rsa, _Float16* wp_gsa, _Float16* wp_fsi, _Float16* wp_fci,
    _Float16* wp_fso, _Float16* wp_fco, _Float16* wp_rsap,
    float* wb_rsa, float* wb_gsa, float* wb_fsi, float* wb_fci)
{
    int bid = blockIdx.x, l = threadIdx.x;
    if      (bid < 24)  wpack_dev(rsa_qkv_w, ln_s0_w, 192, 64, 2, wp_rsa, bid, l);
    else if (bid < 48)  wpack_dev(gsa_qkv_w, ln_c0_w, 192, 64, 2, wp_gsa, bid - 24, l);
    else if (bid < 96)  wpack_dev(ffs_in_w,  ln_s2_w, 340, 64, 2, wp_fsi, bid - 48, l);
    else if (bid < 144) wpack_dev(ffc_in_w,  ln_c2_w, 340, 64, 2, wp_fci, bid - 96, l);
    else if (bid < 168) wpack_dev(ffs_out_w, nullptr, 64, 170, 6, wp_fso, bid - 144, l);
    else if (bid < 192) wpack_dev(ffc_out_w, nullptr, 64, 170, 6, wp_fco, bid - 168, l);
    else if (bid < 200) wpack_dev(rsa_proj_w, nullptr, 64, 64, 2, wp_rsap, bid - 192, l);
    else if (bid < 203) wbias_dev(rsa_qkv_w, ln_s0_b, 192, 192, wb_rsa, bid - 200, l);
    else if (bid < 206) wbias_dev(gsa_qkv_w, ln_c0_b, 192, 192, wb_gsa, bid - 203, l);
    else if (bid < 212) wbias_dev(ffs_in_w, ln_s2_b, 340, 384, wb_fsi, bid - 206, l);
    else                wbias_dev(ffc_in_w, ln_c2_b, 340, 384, wb_fci, bid - 212, l);
}

// =========== transpose x (B,64,N) fp32 -> xT (B,N,64) fp16, LDS-tiled ===========
__global__ __launch_bounds__(256, 1) void xpose_kernel(
    const float* __restrict__ x, _Float16* __restrict__ xT)
{
    __shared__ _Float16 tile[64][72];
    int blk = blockIdx.x;            // b*256 + tile
    int b = blk >> 8, tb = blk & 255;
    int n0 = tb * 64;
    int t = threadIdx.x;
    {
        int ch = t >> 2, seg = t & 3;
        const float* xp = x + ((size_t)b * 64 + ch) * N + n0 + seg * 16;
#pragma unroll
        for (int jj = 0; jj < 4; ++jj) {
            f32x4 v = *(const f32x4*)(xp + jj * 4);
#pragma unroll
            for (int k = 0; k < 4; ++k)
                tile[seg * 16 + jj * 4 + k][ch] = (_Float16)v[k];
        }
    }
    __syncthreads();
    {
        int px = t >> 2, part = t & 3;
        half8 h0 = *(const half8*)&tile[px][part * 16];
        half8 h1 = *(const half8*)&tile[px][part * 16 + 8];
        _Float16* op = xT + ((size_t)b * N + n0 + px) * 64 + part * 16;
        *(half8*)op = h0;
        *(half8*)(op + 8) = h1;
    }
}

// =========== fused LayerNorm + MFMA GEMM (CIN=64), LN affine pre-folded ===========
// 512 threads = 8 waves = 4 row-bands x 2 pixel-halves (each wave: 2 col-groups).
template<int MT, int OREAL, bool ADDIN>
__global__ __launch_bounds__(512, 1) void lngemm_kernel(
    const _Float16* __restrict__ Xp, const _Float16* __restrict__ Rp,
    const float* __restrict__ biasv,
    const _Float16* __restrict__ Wp, _Float16* __restrict__ outp)
{
    __shared__ _Float16 stash[4][MT][16][66];
    int t = threadIdx.x, lane = t & 63, wv = t >> 6;
    int mg = wv & 3, ph = wv >> 2;                    // row band, pixel half
    int pbase = blockIdx.x * 64;
    int b = pbase >> 14, nb = pbase & (N - 1);
    int g = lane >> 4, lm = lane & 15;
    int krow0 = g * 8;

    half8 a[MT][2];
    const _Float16* wb = Wp + (size_t)(mg * MT * 2) * 512 + lane * 8;
#pragma unroll
    for (int mt = 0; mt < MT; ++mt)
#pragma unroll
        for (int kt = 0; kt < 2; ++kt)
            a[mt][kt] = *(const half8*)(wb + (mt * 2 + kt) * 512);

    int rowbase = mg * (MT * 16);
    const float* bp = biasv + rowbase + g * 4;        // L2-resident

    const _Float16* xb = Xp + (size_t)b * N * 64;
    const _Float16* ab = ADDIN ? (Rp + (size_t)b * N * 64) : nullptr;

#pragma unroll
    for (int cg2 = 0; cg2 < 2; ++cg2) {
        int cg = ph * 2 + cg2;
        int col = nb + cg * 16 + lm;
        const _Float16* xp = xb + (size_t)col * 64;
        half8 h0 = *(const half8*)(xp + krow0);
        half8 h1 = *(const half8*)(xp + 32 + krow0);
        float vv[2][8];
        float sm = 0.f, ss = 0.f;
        if (ADDIN) {
            const _Float16* ap = ab + (size_t)col * 64;
            half8 r0 = *(const half8*)(ap + krow0);
            half8 r1 = *(const half8*)(ap + 32 + krow0);
#pragma unroll
            for (int i = 0; i < 8; ++i) {
                float v0 = (float)h0[i] + (float)r0[i];
                float v1 = (float)h1[i] + (float)r1[i];
                vv[0][i] = v0; vv[1][i] = v1;
                sm += v0 + v1; ss += v0 * v0 + v1 * v1;
            }
        } else {
#pragma unroll
            for (int i = 0; i < 8; ++i) {
                float v0 = (float)h0[i], v1 = (float)h1[i];
                vv[0][i] = v0; vv[1][i] = v1;
                sm += v0 + v1; ss += v0 * v0 + v1 * v1;
            }
        }
        sm += __shfl_xor(sm, 16); ss += __shfl_xor(ss, 16);
        sm += __shfl_xor(sm, 32); ss += __shfl_xor(ss, 32);
        float mu = sm * (1.0f / 64.0f);
        float var = ss * (1.0f / 64.0f) - mu * mu;
        float rstd = rsqrtf(var + 1e-5f);
        half8 bf[2];
#pragma unroll
        for (int kt = 0; kt < 2; ++kt)
#pragma unroll
            for (int i = 0; i < 8; ++i)
                bf[kt][i] = (_Float16)((vv[kt][i] - mu) * rstd);

        f32x4 acc[MT];
#pragma unroll
        for (int mt = 0; mt < MT; ++mt) acc[mt] = *(const f32x4*)(bp + mt * 16);
#pragma unroll
        for (int kt = 0; kt < 2; ++kt)
#pragma unroll
            for (int mt = 0; mt < MT; ++mt)
                acc[mt] = __builtin_amdgcn_mfma_f32_16x16x32_f16(a[mt][kt], bf[kt], acc[mt], 0, 0, 0);

#pragma unroll
        for (int mt = 0; mt < MT; ++mt)
#pragma unroll
            for (int r = 0; r < 4; ++r)
                stash[mg][mt][g * 4 + r][cg * 16 + lm] = (_Float16)acc[mt][r];
    }
    __syncthreads();

    // write-back: band-pair (128 threads) per row band; 8 consecutive threads per 128B line
    int tid128 = ph * 64 + lane;
    int row = tid128 >> 3, ch8 = tid128 & 7;
#pragma unroll
    for (int mt = 0; mt < MT; ++mt) {
        int orow = rowbase + mt * 16 + row;
        if ((4 * MT * 16 == OREAL) || orow < OREAL) {
            half8 v0 = *(const half8*)&stash[mg][mt][row][ch8 * 8];
            *(half8*)(outp + ((size_t)b * OREAL + orow) * N + nb + ch8 * 8) = v0;
        }
    }
}

// =========== MFMA conv1x1 GEMM (fp16 channel-major input) ===========
// OUT32: fp32 channel-major out; else fp16 PIXEL-MAJOR out. resid is pixel-major fp16.
template<int MT, int KT, int MG, int NSTRIP, int CIN, int OREAL, int XROWS,
         bool PBW, bool OUT32, bool RESID>
__global__ __launch_bounds__(256, 1) void gemm_kernel(
    const _Float16* __restrict__ X, const _Float16* __restrict__ Wp,
    const _Float16* __restrict__ resid, void* __restrict__ outv)
{
    constexpr int PG = 4 / MG;
    constexpr int PPB = PG * 16 * NSTRIP;
    int t = threadIdx.x;
    int lane = t & 63, wv = t >> 6;
    int mg = wv % MG, pg = wv / MG;
    int pbase = blockIdx.x * PPB;
    int b = pbase >> 14, nb = pbase & (N - 1);

    half8 a[MT][KT];
    const _Float16* wb = Wp + ((size_t)(PBW ? b * (MG * MT * KT) : 0) + mg * MT * KT) * 512 + lane * 8;
#pragma unroll
    for (int mt = 0; mt < MT; ++mt)
#pragma unroll
        for (int kt = 0; kt < KT; ++kt)
            a[mt][kt] = *(const half8*)(wb + (mt * KT + kt) * 512);

    const _Float16* xb = X + (size_t)b * XROWS * N;
    int krow0 = (lane >> 4) * 8;

    for (int s = 0; s < NSTRIP; ++s) {
        int col = nb + (s * PG + pg) * 16 + (lane & 15);
        const _Float16* xp = xb + col;
        half8 bf[KT];
#pragma unroll
        for (int kt = 0; kt < KT; ++kt)
#pragma unroll
            for (int i = 0; i < 8; ++i) {
                int c = kt * 32 + krow0 + i;
                if (KT * 32 <= CIN || c < CIN) bf[kt][i] = xp[(size_t)c * N];
                else bf[kt][i] = (_Float16)0.f;
            }
        f32x4 acc[MT];
#pragma unroll
        for (int mt = 0; mt < MT; ++mt) acc[mt] = (f32x4){0.f, 0.f, 0.f, 0.f};
#pragma unroll
        for (int kt = 0; kt < KT; ++kt)
#pragma unroll
            for (int mt = 0; mt < MT; ++mt)
                acc[mt] = __builtin_amdgcn_mfma_f32_16x16x32_f16(a[mt][kt], bf[kt], acc[mt], 0, 0, 0);

        int orow0 = mg * (MT * 16) + (lane >> 4) * 4;
#pragma unroll
        for (int mt = 0; mt < MT; ++mt) {
            int ob0 = orow0 + mt * 16;
            half4v res;
            if constexpr (RESID)
                res = *(const half4v*)(resid + ((size_t)b * N + col) * 64 + ob0);
            if constexpr (OUT32) {
#pragma unroll
                for (int r = 0; r < 4; ++r) {
                    float vv = acc[mt][r];
                    if constexpr (RESID) vv += (float)res[r];
                    ((float*)outv)[((size_t)b * OREAL + ob0 + r) * N + col] = vv;
                }
            } else {
                half4v h;
#pragma unroll
                for (int r = 0; r < 4; ++r) {
                    float vv = acc[mt][r];
                    if constexpr (RESID) vv += (float)res[r];
                    h[r] = (_Float16)vv;
                }
                *(half4v*)((_Float16*)outv + ((size_t)b * N + col) * 64 + ob0) = h;
            }
        }
    }
}

// =========== depthwise 3x3, packed fp16, 4 rows x 8 px per thread ===========
// Vertical row-quad reuse: 6 row-loads serve 4 output rows. grid (2, B*192).
// ROLLWM: rolled gather (+4 mod 128) + window-major write (for RSA);
// y0 multiple of 4 => all 4 output rows land in the SAME window at p..p+24.
template<bool ROLLWM>
__global__ __launch_bounds__(256, 1) void dw16_kernel(
    const _Float16* __restrict__ in, const float* __restrict__ w,
    _Float16* __restrict__ out)
{
    int bc = blockIdx.y;                 // b*192 + c
    int c = bc % 192;
    int gid = blockIdx.x * 256 + threadIdx.x;   // 0..511
    int yq = gid >> 4;                           // row quad 0..31
    int x0 = (gid & 15) * 8;
    int y0 = yq * 4;                             // output rows y0..y0+3
    const _Float16* ib = in + (size_t)bc * N;
    const float* wr = w + c * 9;         // uniform -> s_load
    _Float16 wh[9];
#pragma unroll
    for (int i = 0; i < 9; ++i) wh[i] = (_Float16)wr[i];

    half8 acc[4];
#pragma unroll
    for (int j = 0; j < 4; ++j) acc[j] = (half8){0, 0, 0, 0, 0, 0, 0, 0};
#pragma unroll
    for (int rr = 0; rr < 6; ++rr) {             // rows y0-1 .. y0+4
        int yy = y0 - 1 + rr;
        if (yy < 0 || yy > 127) continue;
        half8 sL, m, sR;
        if (!ROLLWM) {
            const _Float16* rp = ib + yy * W + x0;
            row_win(rp, x0, sL, m, sR);
        } else {
            int sy = (yy + 4) & 127;
            const _Float16* rp = ib + sy * W;
            if (x0 <= 112) {
                half8 b0 = *(const half8*)(rp + x0);
                half8 b1 = *(const half8*)(rp + x0 + 8);
                sL = __builtin_shufflevector(b0, b1, 3, 4, 5, 6, 7, 8, 9, 10);
                m  = __builtin_shufflevector(b0, b1, 4, 5, 6, 7, 8, 9, 10, 11);
                sR = __builtin_shufflevector(b0, b1, 5, 6, 7, 8, 9, 10, 11, 12);
                if (x0 == 0) sL[0] = (_Float16)0.f;   // xx = -1
            } else {                                   // x0 == 120, wrap path
                _Float16 tmp[10];
#pragma unroll
                for (int j = 0; j < 10; ++j) {
                    int xx = 119 + j;
                    tmp[j] = (xx <= 127) ? rp[(xx + 4) & 127] : (_Float16)0.f;
                }
#pragma unroll
                for (int j = 0; j < 8; ++j) { sL[j] = tmp[j]; m[j] = tmp[j + 1]; sR[j] = tmp[j + 2]; }
            }
        }
#pragma unroll
        for (int j = 0; j < 4; ++j) {
            if (rr >= j && rr <= j + 2) {        // out row y0+j: taps row rr-j
                int tp = (rr - j) * 3;
                acc[j] += sL * wh[tp + 0] + m * wh[tp + 1] + sR * wh[tp + 2];
            }
        }
    }
    if (ROLLWM) {
        int win = ((y0 >> 3) << 4) | (x0 >> 3);
        int p = (y0 & 7) << 3;                   // rows j at p + j*8 (same window)
        _Float16* ob = out + (size_t)bc * N + win * 64 + p;
#pragma unroll
        for (int j = 0; j < 4; ++j) *(half8*)(ob + j * 8) = acc[j];
    } else {
        _Float16* op = out + (size_t)bc * N + y0 * W + x0;
#pragma unroll
        for (int j = 0; j < 4; ++j) *(half8*)(op + j * W) = acc[j];
    }
}

// =========== RSA window attention (MFMA) + fused proj; one block per window ===========
// out = x_ pixel-major (B,N,64) fp16, roll(+4) applied
__global__ __launch_bounds__(256, 3) void rsa_win_kernel(
    const _Float16* __restrict__ qkv, const float* __restrict__ temp_p,
    const _Float16* __restrict__ pwp, _Float16* __restrict__ out)
{
    __shared__ _Float16 qT[64][72];
    __shared__ _Float16 kT[64][72];
    __shared__ _Float16 vP[64][76];
    __shared__ _Float16 aT[64][76];
    __shared__ _Float16 oP[64][76];
    __shared__ float tnorm[128];
    __shared__ _Float16 wsc[64];
    int blk = blockIdx.x, b = blk >> 8, win = blk & 255;
    int t = threadIdx.x, lane = t & 63, wv = t >> 6;
    int g = lane >> 4, lm = lane & 15;

    half8 pa0 = *(const half8*)(pwp + (size_t)(wv * 2 + 0) * 512 + lane * 8);
    half8 pa1 = *(const half8*)(pwp + (size_t)(wv * 2 + 1) * 512 + lane * 8);

    const _Float16* base = qkv + (size_t)b * QKVC * N + win * 64;
    {
        int c = t >> 2, q0 = (t & 3) * 16;
        const _Float16* pq = base + (size_t)c * N + q0;
        half8 a0 = *(const half8*)(pq);
        half8 a1 = *(const half8*)(pq + 8);
        *(half8*)&qT[c][q0] = a0;
        *(half8*)&qT[c][q0 + 8] = a1;
        const _Float16* pk = base + (size_t)(64 + c) * N + q0;
        half8 b0 = *(const half8*)(pk);
        half8 b1 = *(const half8*)(pk + 8);
        *(half8*)&kT[c][q0] = b0;
        *(half8*)&kT[c][q0 + 8] = b1;
        const _Float16* pv = base + (size_t)(128 + c) * N + q0;
        half8 v0 = *(const half8*)(pv);
        half8 v1 = *(const half8*)(pv + 8);
#pragma unroll
        for (int j = 0; j < 8; ++j) vP[q0 + j][c] = v0[j];
#pragma unroll
        for (int j = 0; j < 8; ++j) vP[q0 + 8 + j][c] = v1[j];
    }
    __syncthreads();
    if (t < 128) {
        int p = t & 63;
        float s = 0.f;
        if (t < 64) {
#pragma unroll
            for (int c = 0; c < 64; ++c) { float a = (float)qT[c][p]; s += a * a; }
        } else {
#pragma unroll
            for (int c = 0; c < 64; ++c) { float a = (float)kT[c][p]; s += a * a; }
        }
        tnorm[t] = s;
    }
    __syncthreads();
    if (t < 64) {
        float r = temp_p[0] / (fmaxf(sqrtf(tnorm[t]), 1e-12f) * fmaxf(sqrtf(tnorm[64 + t]), 1e-12f));
        wsc[t] = (_Float16)r;
    }
    __syncthreads();

    {
        half8 aq0 = *(const half8*)&qT[wv * 16 + lm][g * 8];
        half8 aq1 = *(const half8*)&qT[wv * 16 + lm][32 + g * 8];
        half8 ws0 = *(const half8*)&wsc[g * 8];
        half8 ws1 = *(const half8*)&wsc[32 + g * 8];
#pragma unroll
        for (int nt = 0; nt < 4; ++nt) {
            int d = nt * 16 + lm;
            half8 bk0 = *(const half8*)&kT[d][g * 8] * ws0;
            half8 bk1 = *(const half8*)&kT[d][32 + g * 8] * ws1;
            f32x4 acc = {0.f, 0.f, 0.f, 0.f};
            acc = __builtin_amdgcn_mfma_f32_16x16x32_f16(aq0, bk0, acc, 0, 0, 0);
            acc = __builtin_amdgcn_mfma_f32_16x16x32_f16(aq1, bk1, acc, 0, 0, 0);
#pragma unroll
            for (int r = 0; r < 4; ++r)
                aT[wv * 16 + g * 4 + r][d] = (_Float16)fmaxf(acc[r], 0.f);
        }
    }
    __syncthreads();

    {
        half8 a20, a21;
#pragma unroll
        for (int i = 0; i < 8; ++i) {
            a20[i] = aT[g * 8 + i][wv * 16 + lm];
            a21[i] = aT[32 + g * 8 + i][wv * 16 + lm];
        }
#pragma unroll
        for (int nt = 0; nt < 4; ++nt) {
            int p = nt * 16 + lm;
            half4v x0 = *(const half4v*)&vP[p][g * 8];
            half4v x1 = *(const half4v*)&vP[p][g * 8 + 4];
            half4v x2 = *(const half4v*)&vP[p][32 + g * 8];
            half4v x3 = *(const half4v*)&vP[p][32 + g * 8 + 4];
            half8 b20, b21;
#pragma unroll
            for (int j = 0; j < 4; ++j) { b20[j] = x0[j]; b20[4 + j] = x1[j]; b21[j] = x2[j]; b21[4 + j] = x3[j]; }
            f32x4 acc = {0.f, 0.f, 0.f, 0.f};
            acc = __builtin_amdgcn_mfma_f32_16x16x32_f16(a20, b20, acc, 0, 0, 0);
            acc = __builtin_amdgcn_mfma_f32_16x16x32_f16(a21, b21, acc, 0, 0, 0);
#pragma unroll
            for (int r = 0; r < 4; ++r)
                oP[p][wv * 16 + g * 4 + r] = (_Float16)acc[r];
        }
    }
    __syncthreads();

    {
        int y0 = (win >> 4) * 8, x0w = (win & 15) * 8;
        _Float16* ob = out + (size_t)b * N * 64;
#pragma unroll
        for (int nt = 0; nt < 4; ++nt) {
            int p = nt * 16 + lm;
            half4v x0 = *(const half4v*)&oP[p][g * 8];
            half4v x1 = *(const half4v*)&oP[p][g * 8 + 4];
            half4v x2 = *(const half4v*)&oP[p][32 + g * 8];
            half4v x3 = *(const half4v*)&oP[p][32 + g * 8 + 4];
            half8 b30, b31;
#pragma unroll
            for (int j = 0; j < 4; ++j) { b30[j] = x0[j]; b30[4 + j] = x1[j]; b31[j] = x2[j]; b31[4 + j] = x3[j]; }
            f32x4 acc = {0.f, 0.f, 0.f, 0.f};
            acc = __builtin_amdgcn_mfma_f32_16x16x32_f16(pa0, b30, acc, 0, 0, 0);
            acc = __builtin_amdgcn_mfma_f32_16x16x32_f16(pa1, b31, acc, 0, 0, 0);
            int gy = (y0 + (p >> 3) + 4) & 127;
            int gx = (x0w + (p & 7) + 4) & 127;
            half4v h;
#pragma unroll
            for (int r = 0; r < 4; ++r) h[r] = (_Float16)acc[r];
            *(half4v*)(ob + (size_t)(gy * W + gx) * 64 + wv * 16 + g * 4) = h;
        }
    }
}

// =========== FFN stage B: dwconv3x3 + fp16 gelu gate, 4 rows x 8 px per thread ===========
// grid: (2, 170, B); vertical row-quad reuse: 6 row-loads serve 4 output rows
__global__ __launch_bounds__(256, 1) void ffn_b_kernel(
    const _Float16* __restrict__ hid,   // (B,340,N)
    const float* __restrict__ dww,      // (340,9)
    _Float16* __restrict__ gated)       // (B,170,N)
{
    int c = blockIdx.y, b = blockIdx.z;
    int gid = blockIdx.x * 256 + threadIdx.x;   // 0..511
    int yq = gid >> 4;                           // row quad 0..31
    int x0 = (gid & 15) * 8;
    int y0 = yq * 4;                             // output rows y0..y0+3
    const _Float16* pa = hid + ((size_t)b * 340 + c) * N;
    const _Float16* pb = pa + (size_t)170 * N;
    const float* wa = dww + c * 9;               // uniform -> s_load
    const float* wbp = wa + 170 * 9;
    _Float16 wha[9], whb[9];
#pragma unroll
    for (int i = 0; i < 9; ++i) { wha[i] = (_Float16)wa[i]; whb[i] = (_Float16)wbp[i]; }

    half8 aA[4], aB[4];
#pragma unroll
    for (int j = 0; j < 4; ++j) { aA[j] = (half8){0,0,0,0,0,0,0,0}; aB[j] = (half8){0,0,0,0,0,0,0,0}; }
#pragma unroll
    for (int rr = 0; rr < 6; ++rr) {             // rows y0-1 .. y0+4
        int yy = y0 - 1 + rr;
        if (yy < 0 || yy > 127) continue;
        half8 sLa, ma, sRa, sLb, mb, sRb;
        row_win(pa + yy * W + x0, x0, sLa, ma, sRa);
        row_win(pb + yy * W + x0, x0, sLb, mb, sRb);
#pragma unroll
        for (int j = 0; j < 4; ++j) {
            if (rr >= j && rr <= j + 2) {        // out row y0+j: taps row rr-j
                int tp = (rr - j) * 3;
                aA[j] += sLa * wha[tp + 0] + ma * wha[tp + 1] + sRa * wha[tp + 2];
                aB[j] += sLb * whb[tp + 0] + mb * whb[tp + 1] + sRb * whb[tp + 2];
            }
        }
    }
    _Float16* op = gated + ((size_t)b * 170 + c) * N + y0 * W + x0;
#pragma unroll
    for (int j = 0; j < 4; ++j)
        *(half8*)(op + j * W) = gelu_gate_h8(aA[j], aB[j]);
}

// =========== GSA phase A: 2048 px/block (amortized butterfly) ===========
__global__ __launch_bounds__(256, 1) void gsa_part_kernel(
    const _Float16* __restrict__ qkv, float* __restrict__ part)
{
    int bh = blockIdx.y, chunk = blockIdx.x;    // bh in [0,64), chunk in [0,8)
    int b = bh >> 3, h = bh & 7;
    int t = threadIdx.x;
    const _Float16* qb = qkv + ((size_t)b * QKVC + h * 8) * N;
    const _Float16* kb = qb + (size_t)64 * N;
    float acc[80];
#pragma unroll
    for (int j = 0; j < 80; ++j) acc[j] = 0.f;
    for (int i = 0; i < 8; ++i) {
        int n = chunk * 2048 + i * 256 + t;
        float qv[8], kv[8];
#pragma unroll
        for (int c = 0; c < 8; ++c) { qv[c] = (float)qb[(size_t)c * N + n]; kv[c] = (float)kb[(size_t)c * N + n]; }
#pragma unroll
        for (int c = 0; c < 8; ++c) {
            acc[64 + c] += qv[c] * qv[c];
            acc[72 + c] += kv[c] * kv[c];
#pragma unroll
            for (int d = 0; d < 8; ++d) acc[c * 8 + d] += qv[c] * kv[d];
        }
    }
#pragma unroll
    for (int j = 0; j < 80; ++j) {
        float v = acc[j];
#pragma unroll
        for (int m = 1; m < 64; m <<= 1) v += __shfl_xor(v, m, 64);
        acc[j] = v;
    }
    __shared__ float red[4 * 80];
    if ((t & 63) == 0) {
#pragma unroll
        for (int j = 0; j < 80; ++j) red[(t >> 6) * 80 + j] = acc[j];
    }
    __syncthreads();
    if (t < 80) {
        float s = red[t] + red[80 + t] + red[160 + t] + red[240 + t];
        part[((size_t)bh * 8 + chunk) * 80 + t] = s;
    }
}

// =========== GSA finalize: attn + W_eff + fragment pack, one block per batch ===========
__global__ __launch_bounds__(512) void gsa_fin2_kernel(
    const float* __restrict__ part, const float* __restrict__ temp_p,
    const float* __restrict__ pw, _Float16* __restrict__ wp_pbw)
{
    __shared__ float al[512];
    int b = blockIdx.x, tid = threadIdx.x;
    int h = tid >> 6, t64 = tid & 63;
    {
        int bh = b * 8 + h;
        int c = t64 >> 3, d = t64 & 7;
        float S = 0.f, q2 = 0.f, k2 = 0.f;
#pragma unroll
        for (int ch = 0; ch < 8; ++ch) {
            const float* p = part + ((size_t)bh * 8 + ch) * 80;
            S += p[t64]; q2 += p[64 + c]; k2 += p[72 + d];
        }
        float qn = fmaxf(sqrtf(q2), 1e-12f);
        float kn = fmaxf(sqrtf(k2), 1e-12f);
        al[h * 64 + t64] = fmaxf(temp_p[0] * S / (qn * kn), 0.f);
    }
    __syncthreads();
    int f = tid >> 6, l = tid & 63;
    int mt = f >> 1, kt = f & 1;
    int row = mt * 16 + (l & 15);
    int col0 = kt * 32 + (l >> 4) * 8;
    half8 v;
#pragma unroll
    for (int i = 0; i < 8; ++i) {
        int col = col0 + i;
        int hh = col >> 3, dd = col & 7;
        float acc = 0.f;
#pragma unroll
        for (int cc = 0; cc < 8; ++cc)
            acc += pw[row * 64 + cc * 8 + hh] * al[hh * 64 + cc * 8 + dd];
        v[i] = (_Float16)acc;
    }
    *(half8*)(wp_pbw + ((size_t)b * 8 + f) * 512 + l * 8) = v;
}

// =========== sentinel ===========
__global__ void sentinel_kernel(float* out, int n) {
    int i = blockIdx.x * 256 + threadIdx.x;
    if (i < n) out[i] = 12345.0f;
}

extern "C" void kernel_launch(void* const* d_in, const int* in_sizes, int n_in,
                              void* d_out, int out_size, void* d_ws, size_t ws_size,
                              hipStream_t stream)
{
    const float* x         = (const float*)d_in[0];
    const float* ln_s0_w   = (const float*)d_in[1];
    const float* ln_s0_b   = (const float*)d_in[2];
    const float* ln_s2_w   = (const float*)d_in[3];
    const float* ln_s2_b   = (const float*)d_in[4];
    const float* rsa_qkv_w = (const float*)d_in[5];
    const float* rsa_dw_w  = (const float*)d_in[6];
    const float* rsa_proj_w= (const float*)d_in[7];
    const float* rsa_temp  = (const float*)d_in[8];
    const float* ffs_in_w  = (const float*)d_in[9];
    const float* ffs_dw_w  = (const float*)d_in[10];
    const float* ffs_out_w = (const float*)d_in[11];
    const float* ln_c0_w   = (const float*)d_in[12];
    const float* ln_c0_b   = (const float*)d_in[13];
    const float* ln_c2_w   = (const float*)d_in[14];
    const float* ln_c2_b   = (const float*)d_in[15];
    const float* gsa_qkv_w = (const float*)d_in[16];
    const float* gsa_dw_w  = (const float*)d_in[17];
    const float* gsa_proj_w= (const float*)d_in[18];
    const float* gsa_temp  = (const float*)d_in[19];
    const float* ffc_in_w  = (const float*)d_in[20];
    const float* ffc_dw_w  = (const float*)d_in[21];
    const float* ffc_out_w = (const float*)d_in[22];
    float* outp = (float*)d_out;

    // ---- workspace layout (total 168,843,264 B) ----
    char* ws = (char*)d_ws;
    _Float16* tmp192 = (_Float16*)(ws + 0);            // (B,192,N) fp16 [0, 50,331,648)
    _Float16* Qbuf16 = (_Float16*)(ws + 50331648ull);  // (B,192,N) fp16 [50,331,648, 100,663,296)
    _Float16* hidA   = (_Float16*)(ws + 0);            // (B,340,N) fp16 overlay [0, 89,128,960)
    _Float16* gated  = (_Float16*)(ws + 89128960ull);  // (B,170,N) fp16, ends 133,693,440
    _Float16* wp_rsap= (_Float16*)(ws + 133693440ull); // 8,192 B
    _Float16* S2h    = (_Float16*)(ws + 134217728ull); // (B,N,64) fp16 PIXMAJ, ends 150,994,944
    _Float16* X2h    = (_Float16*)(ws + 150994944ull); // (B,N,64) fp16 PIXMAJ, ends 167,772,160
    _Float16* xT     = X2h;                            // xT overlays X2h (dead until gemm fso)
    float*    part   = (float*)(ws + 167772160ull);    // 163,840
    _Float16* wp_rsa = (_Float16*)(ws + 168574976ull); // 24,576
    _Float16* wp_gsa = (_Float16*)(ws + 168599552ull); // 24,576
    _Float16* wp_fsi = (_Float16*)(ws + 168624128ull); // 49,152
    _Float16* wp_fci = (_Float16*)(ws + 168673280ull); // 49,152
    _Float16* wp_fso = (_Float16*)(ws + 168722432ull); // 24,576
    _Float16* wp_fco = (_Float16*)(ws + 168747008ull); // 24,576
    _Float16* wp_pbw = (_Float16*)(ws + 168771584ull); // 65,536 -> ends 168,837,120
    float*    wb_rsa = (float*)(ws + 168837120ull);    // 1,024
    float*    wb_gsa = (float*)(ws + 168838144ull);    // 1,024
    float*    wb_fsi = (float*)(ws + 168839168ull);    // 2,048
    float*    wb_fci = (float*)(ws + 168841216ull);    // 2,048 -> ends 168,843,264
    if (ws_size < 168843264ull) {
        int n = out_size < 4096 ? out_size : 4096;
        sentinel_kernel<<<16, 256, 0, stream>>>(outp, n);
        return;
    }

    dim3 blk256(256), blk512(512);

    // ---- single prep dispatch: all weight packs + LN-fold biases ----
    prep_kernel<<<218, 64, 0, stream>>>(
        rsa_qkv_w, ln_s0_w, ln_s0_b,
        gsa_qkv_w, ln_c0_w, ln_c0_b,
        ffs_in_w,  ln_s2_w, ln_s2_b,
        ffc_in_w,  ln_c2_w, ln_c2_b,
        ffs_out_w, ffc_out_w, rsa_proj_w,
        wp_rsa, wp_gsa, wp_fsi, wp_fci, wp_fso, wp_fco, wp_rsap,
        wb_rsa, wb_gsa, wb_fsi, wb_fci);

    // ---- spatial (RSA) half ----
    xpose_kernel<<<2048, blk256, 0, stream>>>(x, xT);                                        // x -> pixmaj fp16
    lngemm_kernel<3, 192, false><<<2048, blk512, 0, stream>>>(xT, nullptr, wb_rsa, wp_rsa, tmp192);
    dw16_kernel<true><<<dim3(2, B * 192), blk256, 0, stream>>>(tmp192, rsa_dw_w, Qbuf16);    // -> window-major
    rsa_win_kernel<<<2048, blk256, 0, stream>>>(Qbuf16, rsa_temp, wp_rsap, S2h);             // x_ (pixmaj)
    lngemm_kernel<6, 340, true><<<2048, blk512, 0, stream>>>(S2h, xT, wb_fsi, wp_fsi, hidA);
    ffn_b_kernel<<<dim3(2, 170, B), blk256, 0, stream>>>(hidA, ffs_dw_w, gated);
    gemm_kernel<2, 6, 2, 2, 170, 64, 170, false, false, true>
        <<<2048, blk256, 0, stream>>>(gated, wp_fso, S2h, X2h);                              // x (pixmaj, overwrites xT)

    // ---- channel (GSA) half ----
    lngemm_kernel<3, 192, false><<<2048, blk512, 0, stream>>>(X2h, nullptr, wb_gsa, wp_gsa, tmp192);
    dw16_kernel<false><<<dim3(2, B * 192), blk256, 0, stream>>>(tmp192, gsa_dw_w, Qbuf16);   // linear
    gsa_part_kernel<<<dim3(8, 64), blk256, 0, stream>>>(Qbuf16, part);
    gsa_fin2_kernel<<<8, blk512, 0, stream>>>(part, gsa_temp, gsa_proj_w, wp_pbw);           // attn+weff+pack
    gemm_kernel<4, 2, 1, 1, 64, 64, 192, true, false, false>
        <<<2048, blk256, 0, stream>>>(Qbuf16 + (size_t)128 * N, wp_pbw, nullptr, S2h);       // x_ channel (pixmaj)
    lngemm_kernel<6, 340, true><<<2048, blk512, 0, stream>>>(S2h, X2h, wb_fci, wp_fci, hidA);
    ffn_b_kernel<<<dim3(2, 170, B), blk256, 0, stream>>>(hidA, ffc_dw_w, gated);
    gemm_kernel<2, 6, 2, 2, 170, 64, 170, false, true, true>
        <<<2048, blk256, 0, stream>>>(gated, wp_fco, S2h, outp);                             // final fp32
}

// Round 28
// 333.380 us; speedup vs baseline: 1.0152x; 1.0152x over previous
//
#include <hip/hip_runtime.h>
#include <hip/hip_bf16.h>
#include <math.h>

#define DI __device__ __forceinline__

constexpr int B = 8, C = 64, H = 128, W = 128, N = H * W;   // N = 16384
constexpr int HID = 170;
constexpr int QKVC = 3 * C;                                 // 192

typedef _Float16 half8 __attribute__((ext_vector_type(8)));
typedef _Float16 half4v __attribute__((ext_vector_type(4)));
typedef float f32x4 __attribute__((ext_vector_type(4)));

extern "C" __device__ _Float16 __ocml_exp_f16(_Float16);

// gelu exact ~= v * sigmoid(1.5957691*(v + 0.044715 v^3)); fp16 packed path.
DI half8 gelu_gate_h8(half8 a, half8 g) {
    const _Float16 k = (_Float16)0.044715f;
    const _Float16 c = (_Float16)1.5957691f;
    half8 a2 = a * a;
    half8 t = a * ((_Float16)1.f + k * a2);   // packed v_pk ops
    half8 o;
#pragma unroll
    for (int i = 0; i < 8; ++i) {
        _Float16 e = __ocml_exp_f16((_Float16)(-c * t[i]));
        o[i] = (_Float16)(a[i] / ((_Float16)1.f + e) * g[i]);
    }
    return o;
}

// shift-window helper: given aligned row ptr, produce left/center/right windows
DI void row_win(const _Float16* __restrict__ rp, int x0, half8& sL, half8& m, half8& sR) {
    m = *(const half8*)rp;
    half8 pv = {0, 0, 0, 0, 0, 0, 0, 0};
    half8 nv = {0, 0, 0, 0, 0, 0, 0, 0};
    pv[7] = (x0 > 0) ? rp[-1] : (_Float16)0.f;
    nv[0] = (x0 < 120) ? rp[8] : (_Float16)0.f;
    sL = __builtin_shufflevector(pv, m, 7, 8, 9, 10, 11, 12, 13, 14);
    sR = __builtin_shufflevector(m, nv, 1, 2, 3, 4, 5, 6, 7, 8);
}

// ---- device-side weight pack into MFMA A-fragment order (fp32 -> fp16) ----
DI void wpack_dev(const float* __restrict__ Wm, const float* __restrict__ lnsc,
                  int OREAL, int KREAL, int KT, _Float16* __restrict__ out,
                  int f, int l)
{
    int mt = f / KT, kt = f % KT;
    int row = mt * 16 + (l & 15);
    int col0 = kt * 32 + (l >> 4) * 8;
    half8 v;
#pragma unroll
    for (int i = 0; i < 8; ++i) {
        int col = col0 + i;
        float w = (row < OREAL && col < KREAL) ? Wm[row * KREAL + col] : 0.f;
        if (lnsc && col < KREAL) w *= lnsc[col];
        v[i] = (_Float16)w;
    }
    *(half8*)(out + (size_t)f * 512 + l * 8) = v;
}

// ---- device-side bias fold: biasv[o] = sum_c W[o,c]*lnb[c]; zero-pad to OPAD ----
DI void wbias_dev(const float* __restrict__ Wm, const float* __restrict__ lnb,
                  int OREAL, int OPAD, float* __restrict__ biasv, int blk, int l)
{
    int o = blk * 64 + l;
    if (o >= OPAD) return;
    float s = 0.f;
    if (o < OREAL) {
#pragma unroll
        for (int c = 0; c < 64; ++c) s += Wm[o * 64 + c] * lnb[c];
    }
    biasv[o] = s;
}

// =========== single prep kernel: all weight packs + LN-fold biases ===========
__global__ __launch_bounds__(64) void prep_kernel(
    const float* rsa_qkv_w, const float* ln_s0_w, const float* ln_s0_b,
    const float* gsa_qkv_w, const float* ln_c0_w, const float* ln_c0_b,
    const float* ffs_in_w,  const float* ln_s2_w, const float* ln_s2_b,
    const float* ffc_in_w,  const float* ln_c2_w, const float* ln_c2_b,
    const float* ffs_out_w, const float* ffc_out_w, const float* rsa_proj_w,
    _Float16* wp_rsa, _Float16* wp_gsa, _Float16* wp_fsi, _Float16* wp_fci,
    _Float16* wp_fso, _Float16* wp_fco, _Float16* wp_rsap,
    float* wb_rsa, float* wb_gsa, float* wb_fsi, float* wb_fci)
{
    int bid = blockIdx.x, l = threadIdx.x;
    if      (bid < 24)  wpack_dev(rsa_qkv_w, ln_s0_w, 192, 64, 2, wp_rsa, bid, l);
    else if (bid < 48)  wpack_dev(gsa_qkv_w, ln_c0_w, 192, 64, 2, wp_gsa, bid - 24, l);
    else if (bid < 96)  wpack_dev(ffs_in_w,  ln_s2_w, 340, 64, 2, wp_fsi, bid - 48, l);
    else if (bid < 144) wpack_dev(ffc_in_w,  ln_c2_w, 340, 64, 2, wp_fci, bid - 96, l);
    else if (bid < 168) wpack_dev(ffs_out_w, nullptr, 64, 170, 6, wp_fso, bid - 144, l);
    else if (bid < 192) wpack_dev(ffc_out_w, nullptr, 64, 170, 6, wp_fco, bid - 168, l);
    else if (bid < 200) wpack_dev(rsa_proj_w, nullptr, 64, 64, 2, wp_rsap, bid - 192, l);
    else if (bid < 203) wbias_dev(rsa_qkv_w, ln_s0_b, 192, 192, wb_rsa, bid - 200, l);
    else if (bid < 206) wbias_dev(gsa_qkv_w, ln_c0_b, 192, 192, wb_gsa, bid - 203, l);
    else if (bid < 212) wbias_dev(ffs_in_w, ln_s2_b, 340, 384, wb_fsi, bid - 206, l);
    else                wbias_dev(ffc_in_w, ln_c2_b, 340, 384, wb_fci, bid - 212, l);
}

// =========== transpose x (B,64,N) fp32 -> xT (B,N,64) fp16, LDS-tiled ===========
__global__ __launch_bounds__(256, 1) void xpose_kernel(
    const float* __restrict__ x, _Float16* __restrict__ xT)
{
    __shared__ _Float16 tile[64][72];
    int blk = blockIdx.x;            // b*256 + tile
    int b = blk >> 8, tb = blk & 255;
    int n0 = tb * 64;
    int t = threadIdx.x;
    {
        int ch = t >> 2, seg = t & 3;
        const float* xp = x + ((size_t)b * 64 + ch) * N + n0 + seg * 16;
#pragma unroll
        for (int jj = 0; jj < 4; ++jj) {
            f32x4 v = *(const f32x4*)(xp + jj * 4);
#pragma unroll
            for (int k = 0; k < 4; ++k)
                tile[seg * 16 + jj * 4 + k][ch] = (_Float16)v[k];
        }
    }
    __syncthreads();
    {
        int px = t >> 2, part = t & 3;
        half8 h0 = *(const half8*)&tile[px][part * 16];
        half8 h1 = *(const half8*)&tile[px][part * 16 + 8];
        _Float16* op = xT + ((size_t)b * N + n0 + px) * 64 + part * 16;
        *(half8*)op = h0;
        *(half8*)(op + 8) = h1;
    }
}

// =========== fused LayerNorm + MFMA GEMM (CIN=64), LN affine pre-folded ===========
// 512 threads = 8 waves = 4 row-bands x 2 pixel-halves (each wave: 2 col-groups).
template<int MT, int OREAL, bool ADDIN>
__global__ __launch_bounds__(512, 1) void lngemm_kernel(
    const _Float16* __restrict__ Xp, const _Float16* __restrict__ Rp,
    const float* __restrict__ biasv,
    const _Float16* __restrict__ Wp, _Float16* __restrict__ outp)
{
    __shared__ _Float16 stash[4][MT][16][66];
    int t = threadIdx.x, lane = t & 63, wv = t >> 6;
    int mg = wv & 3, ph = wv >> 2;                    // row band, pixel half
    int pbase = blockIdx.x * 64;
    int b = pbase >> 14, nb = pbase & (N - 1);
    int g = lane >> 4, lm = lane & 15;
    int krow0 = g * 8;

    half8 a[MT][2];
    const _Float16* wb = Wp + (size_t)(mg * MT * 2) * 512 + lane * 8;
#pragma unroll
    for (int mt = 0; mt < MT; ++mt)
#pragma unroll
        for (int kt = 0; kt < 2; ++kt)
            a[mt][kt] = *(const half8*)(wb + (mt * 2 + kt) * 512);

    int rowbase = mg * (MT * 16);
    const float* bp = biasv + rowbase + g * 4;        // L2-resident

    const _Float16* xb = Xp + (size_t)b * N * 64;
    const _Float16* ab = ADDIN ? (Rp + (size_t)b * N * 64) : nullptr;

#pragma unroll
    for (int cg2 = 0; cg2 < 2; ++cg2) {
        int cg = ph * 2 + cg2;
        int col = nb + cg * 16 + lm;
        const _Float16* xp = xb + (size_t)col * 64;
        half8 h0 = *(const half8*)(xp + krow0);
        half8 h1 = *(const half8*)(xp + 32 + krow0);
        float vv[2][8];
        float sm = 0.f, ss = 0.f;
        if (ADDIN) {
            const _Float16* ap = ab + (size_t)col * 64;
            half8 r0 = *(const half8*)(ap + krow0);
            half8 r1 = *(const half8*)(ap + 32 + krow0);
#pragma unroll
            for (int i = 0; i < 8; ++i) {
                float v0 = (float)h0[i] + (float)r0[i];
                float v1 = (float)h1[i] + (float)r1[i];
                vv[0][i] = v0; vv[1][i] = v1;
                sm += v0 + v1; ss += v0 * v0 + v1 * v1;
            }
        } else {
#pragma unroll
            for (int i = 0; i < 8; ++i) {
                float v0 = (float)h0[i], v1 = (float)h1[i];
                vv[0][i] = v0; vv[1][i] = v1;
                sm += v0 + v1; ss += v0 * v0 + v1 * v1;
            }
        }
        sm += __shfl_xor(sm, 16); ss += __shfl_xor(ss, 16);
        sm += __shfl_xor(sm, 32); ss += __shfl_xor(ss, 32);
        float mu = sm * (1.0f / 64.0f);
        float var = ss * (1.0f / 64.0f) - mu * mu;
        float rstd = rsqrtf(var + 1e-5f);
        half8 bf[2];
#pragma unroll
        for (int kt = 0; kt < 2; ++kt)
#pragma unroll
            for (int i = 0; i < 8; ++i)
                bf[kt][i] = (_Float16)((vv[kt][i] - mu) * rstd);

        f32x4 acc[MT];
#pragma unroll
        for (int mt = 0; mt < MT; ++mt) acc[mt] = *(const f32x4*)(bp + mt * 16);
#pragma unroll
        for (int kt = 0; kt < 2; ++kt)
#pragma unroll
            for (int mt = 0; mt < MT; ++mt)
                acc[mt] = __builtin_amdgcn_mfma_f32_16x16x32_f16(a[mt][kt], bf[kt], acc[mt], 0, 0, 0);

#pragma unroll
        for (int mt = 0; mt < MT; ++mt)
#pragma unroll
            for (int r = 0; r < 4; ++r)
                stash[mg][mt][g * 4 + r][cg * 16 + lm] = (_Float16)acc[mt][r];
    }
    __syncthreads();

    // write-back: band-pair (128 threads) per row band; 8 consecutive threads per 128B line
    int tid128 = ph * 64 + lane;
    int row = tid128 >> 3, ch8 = tid128 & 7;
#pragma unroll
    for (int mt = 0; mt < MT; ++mt) {
        int orow = rowbase + mt * 16 + row;
        if ((4 * MT * 16 == OREAL) || orow < OREAL) {
            half8 v0 = *(const half8*)&stash[mg][mt][row][ch8 * 8];
            *(half8*)(outp + ((size_t)b * OREAL + orow) * N + nb + ch8 * 8) = v0;
        }
    }
}

// =========== MFMA conv1x1 GEMM (fp16 channel-major input) ===========
// OUT32: fp32 channel-major out; else fp16 PIXEL-MAJOR out. resid is pixel-major fp16.
template<int MT, int KT, int MG, int NSTRIP, int CIN, int OREAL, int XROWS,
         bool PBW, bool OUT32, bool RESID>
__global__ __launch_bounds__(256, 1) void gemm_kernel(
    const _Float16* __restrict__ X, const _Float16* __restrict__ Wp,
    const _Float16* __restrict__ resid, void* __restrict__ outv)
{
    constexpr int PG = 4 / MG;
    constexpr int PPB = PG * 16 * NSTRIP;
    int t = threadIdx.x;
    int lane = t & 63, wv = t >> 6;
    int mg = wv % MG, pg = wv / MG;
    int pbase = blockIdx.x * PPB;
    int b = pbase >> 14, nb = pbase & (N - 1);

    half8 a[MT][KT];
    const _Float16* wb = Wp + ((size_t)(PBW ? b * (MG * MT * KT) : 0) + mg * MT * KT) * 512 + lane * 8;
#pragma unroll
    for (int mt = 0; mt < MT; ++mt)
#pragma unroll
        for (int kt = 0; kt < KT; ++kt)
            a[mt][kt] = *(const half8*)(wb + (mt * KT + kt) * 512);

    const _Float16* xb = X + (size_t)b * XROWS * N;
    int krow0 = (lane >> 4) * 8;

    for (int s = 0; s < NSTRIP; ++s) {
        int col = nb + (s * PG + pg) * 16 + (lane & 15);
        const _Float16* xp = xb + col;
        half8 bf[KT];
#pragma unroll
        for (int kt = 0; kt < KT; ++kt)
#pragma unroll
            for (int i = 0; i < 8; ++i) {
                int c = kt * 32 + krow0 + i;
                if (KT * 32 <= CIN || c < CIN) bf[kt][i] = xp[(size_t)c * N];
                else bf[kt][i] = (_Float16)0.f;
            }
        f32x4 acc[MT];
#pragma unroll
        for (int mt = 0; mt < MT; ++mt) acc[mt] = (f32x4){0.f, 0.f, 0.f, 0.f};
#pragma unroll
        for (int kt = 0; kt < KT; ++kt)
#pragma unroll
            for (int mt = 0; mt < MT; ++mt)
                acc[mt] = __builtin_amdgcn_mfma_f32_16x16x32_f16(a[mt][kt], bf[kt], acc[mt], 0, 0, 0);

        int orow0 = mg * (MT * 16) + (lane >> 4) * 4;
#pragma unroll
        for (int mt = 0; mt < MT; ++mt) {
            int ob0 = orow0 + mt * 16;
            half4v res;
            if constexpr (RESID)
                res = *(const half4v*)(resid + ((size_t)b * N + col) * 64 + ob0);
            if constexpr (OUT32) {
#pragma unroll
                for (int r = 0; r < 4; ++r) {
                    float vv = acc[mt][r];
                    if constexpr (RESID) vv += (float)res[r];
                    ((float*)outv)[((size_t)b * OREAL + ob0 + r) * N + col] = vv;
                }
            } else {
                half4v h;
#pragma unroll
                for (int r = 0; r < 4; ++r) {
                    float vv = acc[mt][r];
                    if constexpr (RESID) vv += (float)res[r];
                    h[r] = (_Float16)vv;
                }
                *(half4v*)((_Float16*)outv + ((size_t)b * N + col) * 64 + ob0) = h;
            }
        }
    }
}

// =========== depthwise 3x3, packed fp16, 2 rows x 8 px per thread ===========
// Vertical row-pair reuse: 4 row-loads serve 2 output rows (was 6). grid (4, B*192).
// ROLLWM: rolled gather (+4 mod 128) + window-major write (for RSA);
// y0 even => both output rows land in the SAME window at p and p+8.
template<bool ROLLWM>
__global__ __launch_bounds__(256, 1) void dw16_kernel(
    const _Float16* __restrict__ in, const float* __restrict__ w,
    _Float16* __restrict__ out)
{
    int bc = blockIdx.y;                 // b*192 + c
    int c = bc % 192;
    int gid = blockIdx.x * 256 + threadIdx.x;   // 0..1023
    int yp = gid >> 4;                           // row pair 0..63
    int x0 = (gid & 15) * 8;
    int y0 = yp * 2;                             // output rows y0, y0+1
    const _Float16* ib = in + (size_t)bc * N;
    const float* wr = w + c * 9;         // uniform -> s_load
    _Float16 wh[9];
#pragma unroll
    for (int i = 0; i < 9; ++i) wh[i] = (_Float16)wr[i];

    half8 acc0 = {0, 0, 0, 0, 0, 0, 0, 0};
    half8 acc1 = {0, 0, 0, 0, 0, 0, 0, 0};
#pragma unroll
    for (int rr = 0; rr < 4; ++rr) {             // rows y0-1 .. y0+2
        int yy = y0 - 1 + rr;
        if (yy < 0 || yy > 127) continue;
        half8 sL, m, sR;
        if (!ROLLWM) {
            const _Float16* rp = ib + yy * W + x0;
            row_win(rp, x0, sL, m, sR);
        } else {
            int sy = (yy + 4) & 127;
            const _Float16* rp = ib + sy * W;
            if (x0 <= 112) {
                half8 b0 = *(const half8*)(rp + x0);
                half8 b1 = *(const half8*)(rp + x0 + 8);
                sL = __builtin_shufflevector(b0, b1, 3, 4, 5, 6, 7, 8, 9, 10);
                m  = __builtin_shufflevector(b0, b1, 4, 5, 6, 7, 8, 9, 10, 11);
                sR = __builtin_shufflevector(b0, b1, 5, 6, 7, 8, 9, 10, 11, 12);
                if (x0 == 0) sL[0] = (_Float16)0.f;   // xx = -1
            } else {                                   // x0 == 120, wrap path
                _Float16 tmp[10];
#pragma unroll
                for (int j = 0; j < 10; ++j) {
                    int xx = 119 + j;
                    tmp[j] = (xx <= 127) ? rp[(xx + 4) & 127] : (_Float16)0.f;
                }
#pragma unroll
                for (int j = 0; j < 8; ++j) { sL[j] = tmp[j]; m[j] = tmp[j + 1]; sR[j] = tmp[j + 2]; }
            }
        }
        if (rr <= 2)                             // out row y0: taps row rr
            acc0 += sL * wh[rr * 3 + 0] + m * wh[rr * 3 + 1] + sR * wh[rr * 3 + 2];
        if (rr >= 1)                             // out row y0+1: taps row rr-1
            acc1 += sL * wh[(rr - 1) * 3 + 0] + m * wh[(rr - 1) * 3 + 1] + sR * wh[(rr - 1) * 3 + 2];
    }
    if (ROLLWM) {
        int win = ((y0 >> 3) << 4) | (x0 >> 3);
        int p = (y0 & 7) << 3;                   // 8 px = one window row; row y0+1 at p+8
        _Float16* ob = out + (size_t)bc * N + win * 64 + p;
        *(half8*)ob = acc0;
        *(half8*)(ob + 8) = acc1;
    } else {
        _Float16* op = out + (size_t)bc * N + y0 * W + x0;
        *(half8*)op = acc0;
        *(half8*)(op + W) = acc1;
    }
}

// =========== RSA window attention (MFMA) + fused proj; one block per window ===========
// out = x_ pixel-major (B,N,64) fp16, roll(+4) applied
__global__ __launch_bounds__(256, 3) void rsa_win_kernel(
    const _Float16* __restrict__ qkv, const float* __restrict__ temp_p,
    const _Float16* __restrict__ pwp, _Float16* __restrict__ out)
{
    __shared__ _Float16 qT[64][72];
    __shared__ _Float16 kT[64][72];
    __shared__ _Float16 vP[64][76];
    __shared__ _Float16 aT[64][76];
    __shared__ _Float16 oP[64][76];
    __shared__ float tnorm[128];
    __shared__ _Float16 wsc[64];
    int blk = blockIdx.x, b = blk >> 8, win = blk & 255;
    int t = threadIdx.x, lane = t & 63, wv = t >> 6;
    int g = lane >> 4, lm = lane & 15;

    half8 pa0 = *(const half8*)(pwp + (size_t)(wv * 2 + 0) * 512 + lane * 8);
    half8 pa1 = *(const half8*)(pwp + (size_t)(wv * 2 + 1) * 512 + lane * 8);

    const _Float16* base = qkv + (size_t)b * QKVC * N + win * 64;
    {
        int c = t >> 2, q0 = (t & 3) * 16;
        const _Float16* pq = base + (size_t)c * N + q0;
        half8 a0 = *(const half8*)(pq);
        half8 a1 = *(const half8*)(pq + 8);
        *(half8*)&qT[c][q0] = a0;
        *(half8*)&qT[c][q0 + 8] = a1;
        const _Float16* pk = base + (size_t)(64 + c) * N + q0;
        half8 b0 = *(const half8*)(pk);
        half8 b1 = *(const half8*)(pk + 8);
        *(half8*)&kT[c][q0] = b0;
        *(half8*)&kT[c][q0 + 8] = b1;
        const _Float16* pv = base + (size_t)(128 + c) * N + q0;
        half8 v0 = *(const half8*)(pv);
        half8 v1 = *(const half8*)(pv + 8);
#pragma unroll
        for (int j = 0; j < 8; ++j) vP[q0 + j][c] = v0[j];
#pragma unroll
        for (int j = 0; j < 8; ++j) vP[q0 + 8 + j][c] = v1[j];
    }
    __syncthreads();
    if (t < 128) {
        int p = t & 63;
        float s = 0.f;
        if (t < 64) {
#pragma unroll
            for (int c = 0; c < 64; ++c) { float a = (float)qT[c][p]; s += a * a; }
        } else {
#pragma unroll
            for (int c = 0; c < 64; ++c) { float a = (float)kT[c][p]; s += a * a; }
        }
        tnorm[t] = s;
    }
    __syncthreads();
    if (t < 64) {
        float r = temp_p[0] / (fmaxf(sqrtf(tnorm[t]), 1e-12f) * fmaxf(sqrtf(tnorm[64 + t]), 1e-12f));
        wsc[t] = (_Float16)r;
    }
    __syncthreads();

    {
        half8 aq0 = *(const half8*)&qT[wv * 16 + lm][g * 8];
        half8 aq1 = *(const half8*)&qT[wv * 16 + lm][32 + g * 8];
        half8 ws0 = *(const half8*)&wsc[g * 8];
        half8 ws1 = *(const half8*)&wsc[32 + g * 8];
#pragma unroll
        for (int nt = 0; nt < 4; ++nt) {
            int d = nt * 16 + lm;
            half8 bk0 = *(const half8*)&kT[d][g * 8] * ws0;
            half8 bk1 = *(const half8*)&kT[d][32 + g * 8] * ws1;
            f32x4 acc = {0.f, 0.f, 0.f, 0.f};
            acc = __builtin_amdgcn_mfma_f32_16x16x32_f16(aq0, bk0, acc, 0, 0, 0);
            acc = __builtin_amdgcn_mfma_f32_16x16x32_f16(aq1, bk1, acc, 0, 0, 0);
#pragma unroll
            for (int r = 0; r < 4; ++r)
                aT[wv * 16 + g * 4 + r][d] = (_Float16)fmaxf(acc[r], 0.f);
        }
    }
    __syncthreads();

    {
        half8 a20, a21;
#pragma unroll
        for (int i = 0; i < 8; ++i) {
            a20[i] = aT[g * 8 + i][wv * 16 + lm];
            a21[i] = aT[32 + g * 8 + i][wv * 16 + lm];
        }
#pragma unroll
        for (int nt = 0; nt < 4; ++nt) {
            int p = nt * 16 + lm;
            half4v x0 = *(const half4v*)&vP[p][g * 8];
            half4v x1 = *(const half4v*)&vP[p][g * 8 + 4];
            half4v x2 = *(const half4v*)&vP[p][32 + g * 8];
            half4v x3 = *(const half4v*)&vP[p][32 + g * 8 + 4];
            half8 b20, b21;
#pragma unroll
            for (int j = 0; j < 4; ++j) { b20[j] = x0[j]; b20[4 + j] = x1[j]; b21[j] = x2[j]; b21[4 + j] = x3[j]; }
            f32x4 acc = {0.f, 0.f, 0.f, 0.f};
            acc = __builtin_amdgcn_mfma_f32_16x16x32_f16(a20, b20, acc, 0, 0, 0);
            acc = __builtin_amdgcn_mfma_f32_16x16x32_f16(a21, b21, acc, 0, 0, 0);
#pragma unroll
            for (int r = 0; r < 4; ++r)
                oP[p][wv * 16 + g * 4 + r] = (_Float16)acc[r];
        }
    }
    __syncthreads();

    {
        int y0 = (win >> 4) * 8, x0w = (win & 15) * 8;
        _Float16* ob = out + (size_t)b * N * 64;
#pragma unroll
        for (int nt = 0; nt < 4; ++nt) {
            int p = nt * 16 + lm;
            half4v x0 = *(const half4v*)&oP[p][g * 8];
            half4v x1 = *(const half4v*)&oP[p][g * 8 + 4];
            half4v x2 = *(const half4v*)&oP[p][32 + g * 8];
            half4v x3 = *(const half4v*)&oP[p][32 + g * 8 + 4];
            half8 b30, b31;
#pragma unroll
            for (int j = 0; j < 4; ++j) { b30[j] = x0[j]; b30[4 + j] = x1[j]; b31[j] = x2[j]; b31[4 + j] = x3[j]; }
            f32x4 acc = {0.f, 0.f, 0.f, 0.f};
            acc = __builtin_amdgcn_mfma_f32_16x16x32_f16(pa0, b30, acc, 0, 0, 0);
            acc = __builtin_amdgcn_mfma_f32_16x16x32_f16(pa1, b31, acc, 0, 0, 0);
            int gy = (y0 + (p >> 3) + 4) & 127;
            int gx = (x0w + (p & 7) + 4) & 127;
            half4v h;
#pragma unroll
            for (int r = 0; r < 4; ++r) h[r] = (_Float16)acc[r];
            *(half4v*)(ob + (size_t)(gy * W + gx) * 64 + wv * 16 + g * 4) = h;
        }
    }
}

// =========== FFN stage B: dwconv3x3 + fp16 gelu gate, 2 rows x 8 px per thread ===========
// grid: (4, 170, B); vertical row-pair reuse: 4 row-loads serve 2 output rows
__global__ __launch_bounds__(256, 1) void ffn_b_kernel(
    const _Float16* __restrict__ hid,   // (B,340,N)
    const float* __restrict__ dww,      // (340,9)
    _Float16* __restrict__ gated)       // (B,170,N)
{
    int c = blockIdx.y, b = blockIdx.z;
    int gid = blockIdx.x * 256 + threadIdx.x;   // 0..1023
    int yp = gid >> 4;                           // row pair 0..63
    int x0 = (gid & 15) * 8;
    int y0 = yp * 2;                             // output rows y0, y0+1
    const _Float16* pa = hid + ((size_t)b * 340 + c) * N;
    const _Float16* pb = pa + (size_t)170 * N;
    const float* wa = dww + c * 9;               // uniform -> s_load
    const float* wbp = wa + 170 * 9;
    _Float16 wha[9], whb[9];
#pragma unroll
    for (int i = 0; i < 9; ++i) { wha[i] = (_Float16)wa[i]; whb[i] = (_Float16)wbp[i]; }

    half8 aA0 = {0,0,0,0,0,0,0,0}, aA1 = {0,0,0,0,0,0,0,0};
    half8 aB0 = {0,0,0,0,0,0,0,0}, aB1 = {0,0,0,0,0,0,0,0};
#pragma unroll
    for (int rr = 0; rr < 4; ++rr) {             // rows y0-1 .. y0+2
        int yy = y0 - 1 + rr;
        if (yy < 0 || yy > 127) continue;
        half8 sLa, ma, sRa, sLb, mb, sRb;
        row_win(pa + yy * W + x0, x0, sLa, ma, sRa);
        row_win(pb + yy * W + x0, x0, sLb, mb, sRb);
        if (rr <= 2) {                           // out row y0: taps row rr
            aA0 += sLa * wha[rr * 3 + 0] + ma * wha[rr * 3 + 1] + sRa * wha[rr * 3 + 2];
            aB0 += sLb * whb[rr * 3 + 0] + mb * whb[rr * 3 + 1] + sRb * whb[rr * 3 + 2];
        }
        if (rr >= 1) {                           // out row y0+1: taps row rr-1
            aA1 += sLa * wha[(rr - 1) * 3 + 0] + ma * wha[(rr - 1) * 3 + 1] + sRa * wha[(rr - 1) * 3 + 2];
            aB1 += sLb * whb[(rr - 1) * 3 + 0] + mb * whb[(rr - 1) * 3 + 1] + sRb * whb[(rr - 1) * 3 + 2];
        }
    }
    _Float16* op = gated + ((size_t)b * 170 + c) * N + y0 * W + x0;
    *(half8*)op = gelu_gate_h8(aA0, aB0);
    *(half8*)(op + W) = gelu_gate_h8(aA1, aB1);
}

// =========== GSA phase A: 2048 px/block (amortized butterfly) ===========
__global__ __launch_bounds__(256, 1) void gsa_part_kernel(
    const _Float16* __restrict__ qkv, float* __restrict__ part)
{
    int bh = blockIdx.y, chunk = blockIdx.x;    // bh in [0,64), chunk in [0,8)
    int b = bh >> 3, h = bh & 7;
    int t = threadIdx.x;
    const _Float16* qb = qkv + ((size_t)b * QKVC + h * 8) * N;
    const _Float16* kb = qb + (size_t)64 * N;
    float acc[80];
#pragma unroll
    for (int j = 0; j < 80; ++j) acc[j] = 0.f;
    for (int i = 0; i < 8; ++i) {
        int n = chunk * 2048 + i * 256 + t;
        float qv[8], kv[8];
#pragma unroll
        for (int c = 0; c < 8; ++c) { qv[c] = (float)qb[(size_t)c * N + n]; kv[c] = (float)kb[(size_t)c * N + n]; }
#pragma unroll
        for (int c = 0; c < 8; ++c) {
            acc[64 + c] += qv[c] * qv[c];
            acc[72 + c] += kv[c] * kv[c];
#pragma unroll
            for (int d = 0; d < 8; ++d) acc[c * 8 + d] += qv[c] * kv[d];
        }
    }
#pragma unroll
    for (int j = 0; j < 80; ++j) {
        float v = acc[j];
#pragma unroll
        for (int m = 1; m < 64; m <<= 1) v += __shfl_xor(v, m, 64);
        acc[j] = v;
    }
    __shared__ float red[4 * 80];
    if ((t & 63) == 0) {
#pragma unroll
        for (int j = 0; j < 80; ++j) red[(t >> 6) * 80 + j] = acc[j];
    }
    __syncthreads();
    if (t < 80) {
        float s = red[t] + red[80 + t] + red[160 + t] + red[240 + t];
        part[((size_t)bh * 8 + chunk) * 80 + t] = s;
    }
}

// =========== GSA finalize: attn + W_eff + fragment pack, one block per batch ===========
__global__ __launch_bounds__(512) void gsa_fin2_kernel(
    const float* __restrict__ part, const float* __restrict__ temp_p,
    const float* __restrict__ pw, _Float16* __restrict__ wp_pbw)
{
    __shared__ float al[512];
    int b = blockIdx.x, tid = threadIdx.x;
    int h = tid >> 6, t64 = tid & 63;
    {
        int bh = b * 8 + h;
        int c = t64 >> 3, d = t64 & 7;
        float S = 0.f, q2 = 0.f, k2 = 0.f;
#pragma unroll
        for (int ch = 0; ch < 8; ++ch) {
            const float* p = part + ((size_t)bh * 8 + ch) * 80;
            S += p[t64]; q2 += p[64 + c]; k2 += p[72 + d];
        }
        float qn = fmaxf(sqrtf(q2), 1e-12f);
        float kn = fmaxf(sqrtf(k2), 1e-12f);
        al[h * 64 + t64] = fmaxf(temp_p[0] * S / (qn * kn), 0.f);
    }
    __syncthreads();
    int f = tid >> 6, l = tid & 63;
    int mt = f >> 1, kt = f & 1;
    int row = mt * 16 + (l & 15);
    int col0 = kt * 32 + (l >> 4) * 8;
    half8 v;
#pragma unroll
    for (int i = 0; i < 8; ++i) {
        int col = col0 + i;
        int hh = col >> 3, dd = col & 7;
        float acc = 0.f;
#pragma unroll
        for (int cc = 0; cc < 8; ++cc)
            acc += pw[row * 64 + cc * 8 + hh] * al[hh * 64 + cc * 8 + dd];
        v[i] = (_Float16)acc;
    }
    *(half8*)(wp_pbw + ((size_t)b * 8 + f) * 512 + l * 8) = v;
}

// =========== sentinel ===========
__global__ void sentinel_kernel(float* out, int n) {
    int i = blockIdx.x * 256 + threadIdx.x;
    if (i < n) out[i] = 12345.0f;
}

extern "C" void kernel_launch(void* const* d_in, const int* in_sizes, int n_in,
                              void* d_out, int out_size, void* d_ws, size_t ws_size,
                              hipStream_t stream)
{
    const float* x         = (const float*)d_in[0];
    const float* ln_s0_w   = (const float*)d_in[1];
    const float* ln_s0_b   = (const float*)d_in[2];
    const float* ln_s2_w   = (const float*)d_in[3];
    const float* ln_s2_b   = (const float*)d_in[4];
    const float* rsa_qkv_w = (const float*)d_in[5];
    const float* rsa_dw_w  = (const float*)d_in[6];
    const float* rsa_proj_w= (const float*)d_in[7];
    const float* rsa_temp  = (const float*)d_in[8];
    const float* ffs_in_w  = (const float*)d_in[9];
    const float* ffs_dw_w  = (const float*)d_in[10];
    const float* ffs_out_w = (const float*)d_in[11];
    const float* ln_c0_w   = (const float*)d_in[12];
    const float* ln_c0_b   = (const float*)d_in[13];
    const float* ln_c2_w   = (const float*)d_in[14];
    const float* ln_c2_b   = (const float*)d_in[15];
    const float* gsa_qkv_w = (const float*)d_in[16];
    const float* gsa_dw_w  = (const float*)d_in[17];
    const float* gsa_proj_w= (const float*)d_in[18];
    const float* gsa_temp  = (const float*)d_in[19];
    const float* ffc_in_w  = (const float*)d_in[20];
    const float* ffc_dw_w  = (const float*)d_in[21];
    const float* ffc_out_w = (const float*)d_in[22];
    float* outp = (float*)d_out;

    // ---- workspace layout (total 168,843,264 B) ----
    char* ws = (char*)d_ws;
    _Float16* tmp192 = (_Float16*)(ws + 0);            // (B,192,N) fp16 [0, 50,331,648)
    _Float16* Qbuf16 = (_Float16*)(ws + 50331648ull);  // (B,192,N) fp16 [50,331,648, 100,663,296)
    _Float16* hidA   = (_Float16*)(ws + 0);            // (B,340,N) fp16 overlay [0, 89,128,960)
    _Float16* gated  = (_Float16*)(ws + 89128960ull);  // (B,170,N) fp16, ends 133,693,440
    _Float16* wp_rsap= (_Float16*)(ws + 133693440ull); // 8,192 B
    _Float16* S2h    = (_Float16*)(ws + 134217728ull); // (B,N,64) fp16 PIXMAJ, ends 150,994,944
    _Float16* X2h    = (_Float16*)(ws + 150994944ull); // (B,N,64) fp16 PIXMAJ, ends 167,772,160
    _Float16* xT     = X2h;                            // xT overlays X2h (dead until gemm fso)
    float*    part   = (float*)(ws + 167772160ull);    // 163,840
    _Float16* wp_rsa = (_Float16*)(ws + 168574976ull); // 24,576
    _Float16* wp_gsa = (_Float16*)(ws + 168599552ull); // 24,576
    _Float16* wp_fsi = (_Float16*)(ws + 168624128ull); // 49,152
    _Float16* wp_fci = (_Float16*)(ws + 168673280ull); // 49,152
    _Float16* wp_fso = (_Float16*)(ws + 168722432ull); // 24,576
    _Float16* wp_fco = (_Float16*)(ws + 168747008ull); // 24,576
    _Float16* wp_pbw = (_Float16*)(ws + 168771584ull); // 65,536 -> ends 168,837,120
    float*    wb_rsa = (float*)(ws + 168837120ull);    // 1,024
    float*    wb_gsa = (float*)(ws + 168838144ull);    // 1,024
    float*    wb_fsi = (float*)(ws + 168839168ull);    // 2,048
    float*    wb_fci = (float*)(ws + 168841216ull);    // 2,048 -> ends 168,843,264
    if (ws_size < 168843264ull) {
        int n = out_size < 4096 ? out_size : 4096;
        sentinel_kernel<<<16, 256, 0, stream>>>(outp, n);
        return;
    }

    dim3 blk256(256), blk512(512);

    // ---- single prep dispatch: all weight packs + LN-fold biases ----
    prep_kernel<<<218, 64, 0, stream>>>(
        rsa_qkv_w, ln_s0_w, ln_s0_b,
        gsa_qkv_w, ln_c0_w, ln_c0_b,
        ffs_in_w,  ln_s2_w, ln_s2_b,
        ffc_in_w,  ln_c2_w, ln_c2_b,
        ffs_out_w, ffc_out_w, rsa_proj_w,
        wp_rsa, wp_gsa, wp_fsi, wp_fci, wp_fso, wp_fco, wp_rsap,
        wb_rsa, wb_gsa, wb_fsi, wb_fci);

    // ---- spatial (RSA) half ----
    xpose_kernel<<<2048, blk256, 0, stream>>>(x, xT);                                        // x -> pixmaj fp16
    lngemm_kernel<3, 192, false><<<2048, blk512, 0, stream>>>(xT, nullptr, wb_rsa, wp_rsa, tmp192);
    dw16_kernel<true><<<dim3(4, B * 192), blk256, 0, stream>>>(tmp192, rsa_dw_w, Qbuf16);    // -> window-major
    rsa_win_kernel<<<2048, blk256, 0, stream>>>(Qbuf16, rsa_temp, wp_rsap, S2h);             // x_ (pixmaj)
    lngemm_kernel<6, 340, true><<<2048, blk512, 0, stream>>>(S2h, xT, wb_fsi, wp_fsi, hidA);
    ffn_b_kernel<<<dim3(4, 170, B), blk256, 0, stream>>>(hidA, ffs_dw_w, gated);
    gemm_kernel<2, 6, 2, 2, 170, 64, 170, false, false, true>
        <<<2048, blk256, 0, stream>>>(gated, wp_fso, S2h, X2h);                              // x (pixmaj, overwrites xT)

    // ---- channel (GSA) half ----
    lngemm_kernel<3, 192, false><<<2048, blk512, 0, stream>>>(X2h, nullptr, wb_gsa, wp_gsa, tmp192);
    dw16_kernel<false><<<dim3(4, B * 192), blk256, 0, stream>>>(tmp192, gsa_dw_w, Qbuf16);   // linear
    gsa_part_kernel<<<dim3(8, 64), blk256, 0, stream>>>(Qbuf16, part);
    gsa_fin2_kernel<<<8, blk512, 0, stream>>>(part, gsa_temp, gsa_proj_w, wp_pbw);           // attn+weff+pack
    gemm_kernel<4, 2, 1, 1, 64, 64, 192, true, false, false>
        <<<2048, blk256, 0, stream>>>(Qbuf16 + (size_t)128 * N, wp_pbw, nullptr, S2h);       // x_ channel (pixmaj)
    lngemm_kernel<6, 340, true><<<2048, blk512, 0, stream>>>(S2h, X2h, wb_fci, wp_fci, hidA);
    ffn_b_kernel<<<dim3(4, 170, B), blk256, 0, stream>>>(hidA, ffc_dw_w, gated);
    gemm_kernel<2, 6, 2, 2, 170, 64, 170, false, true, true>
        <<<2048, blk256, 0, stream>>>(gated, wp_fco, S2h, outp);                             // final fp32
}